// Round 5
// baseline (1098.892 us; speedup 1.0000x reference)
//
#include <hip/hip_runtime.h>

// GCN 2-layer: N=100000, F=128 -> H=16 (relu) -> C=40, E=3200000.
// R4 -> R5: atomic scatter is pinned at the L2 atomic-op ceiling
// (306 G-ops/s = 8 XCD x 16 ch x 2.4GHz; R2 = 2x167us). Replace with
// bin-grouped GATHER aggregation:
//   - nodes in bins of 64; edges grouped by bin only (no per-node sort),
//     entry = src | (dst&63)<<17 in one u32.
//   - bucket-fill writes are XCD-sharded (cursor per (bin, blockIdx&7)) so
//     each ~1.6MB shard region is written by one XCD and dirty lines merge
//     in its L2 (R3's unsharded fill paid 1 full-line writeback per 4B).
//   - agg kernel: LDS acc rows (64x16 fl), LDS float atomics, coalesced
//     row gathers of vs[src] (read-only randomness -> L2/L3), coalesced
//     epilogue store. Zero global float atomics.
// Pre-scale trick kept: vs = dinv*h; agg_raw[n] = sum vs[src] + vs[n];
// consumer applies dinv[n]. Layer-1 epilogue fuses relu+rescale (no k_mid).

#define N_NODES 100000
#define F_IN    128
#define H_MID   16
#define C_OUT   40
#define N_EDGES 3200000

#define BIN_SH   6
#define BIN_N    64                      // nodes per bin
#define NBINS    1563                    // ceil(100000/64)
#define NSEG     (NBINS * 8)             // per-(bin,shard) segments
#define FILL_B   1024                    // fill/hist blocks
#define T_FILL   3125                    // edges per fill block (1024*3125 = E exact)

__global__ void k_zero(int* __restrict__ cnt, int* __restrict__ histG) {
    int i = blockIdx.x * 256 + threadIdx.x;
    if (i < N_NODES) cnt[i] = 0;
    if (i < NSEG)    histG[i] = 0;
}

__global__ void k_count(const int* __restrict__ dst, int* __restrict__ cnt) {
    int e = blockIdx.x * 256 + threadIdx.x;
    if (e < N_EDGES) atomicAdd(&cnt[dst[e]], 1);
}

__global__ void k_dinv(const int* __restrict__ cnt, float* __restrict__ dinv) {
    int i = blockIdx.x * 256 + threadIdx.x;
    if (i < N_NODES) dinv[i] = rsqrtf(1.0f + (float)cnt[i]);   // +1 = self loop
}

// Per-block LDS histogram over bins, flushed to histG[bin*8 + shard].
__global__ void __launch_bounds__(256) k_hist(const int* __restrict__ dst,
                                              int* __restrict__ histG) {
    __shared__ int h[NBINS];
    int t = threadIdx.x;
    for (int i = t; i < NBINS; i += 256) h[i] = 0;
    __syncthreads();
    size_t e0 = (size_t)blockIdx.x * T_FILL;
    for (int i = t; i < T_FILL; i += 256)
        atomicAdd(&h[dst[e0 + i] >> BIN_SH], 1);
    __syncthreads();
    int shard = blockIdx.x & 7;
    for (int i = t; i < NBINS; i += 256)
        if (h[i]) atomicAdd(&histG[i * 8 + shard], h[i]);
}

// Exclusive scan of histG[NSEG] -> off (+ total at off[NSEG]), cursor copy.
__global__ void __launch_bounds__(1024) k_scan(const int* __restrict__ histG,
                                               int* __restrict__ off,
                                               int* __restrict__ cursor) {
    __shared__ int s[1024];
    const int CH = (NSEG + 1023) / 1024;       // 13
    int t = threadIdx.x;
    int base = t * CH;
    int loc[13];
    int sum = 0;
    for (int i = 0; i < CH; ++i) {
        int idx = base + i;
        int v = (idx < NSEG) ? histG[idx] : 0;
        loc[i] = sum; sum += v;
    }
    s[t] = sum;
    __syncthreads();
    for (int o = 1; o < 1024; o <<= 1) {       // Hillis-Steele inclusive
        int v = (t >= o) ? s[t - o] : 0;
        __syncthreads();
        s[t] += v;
        __syncthreads();
    }
    int pre = (t > 0) ? s[t - 1] : 0;
    for (int i = 0; i < CH; ++i) {
        int idx = base + i;
        if (idx < NSEG) { int o = pre + loc[i]; off[idx] = o; cursor[idx] = o; }
    }
    if (t == 1023) off[NSEG] = pre + sum;      // == E
}

// Fill packed bin segments. shard = blockIdx&7 ~ XCD (round-robin heuristic):
// each shard's regions are written by one XCD -> dirty lines merge in its L2.
__global__ void __launch_bounds__(256) k_binfill(const int* __restrict__ src,
                                                 const int* __restrict__ dst,
                                                 int* __restrict__ cursor,
                                                 unsigned* __restrict__ packed) {
    int shard = blockIdx.x & 7;
    size_t e0 = (size_t)blockIdx.x * T_FILL;
    for (int i = threadIdx.x; i < T_FILL; i += 256) {
        int d = dst[e0 + i];
        int s = src[e0 + i];
        int bin = d >> BIN_SH;
        int pos = atomicAdd(&cursor[bin * 8 + shard], 1);
        packed[pos] = (unsigned)s | ((unsigned)(d & (BIN_N - 1)) << 17);
    }
}

// vs1 = dinv*(x@W1). 16 nodes x 16 feats per 256-thread block.
__global__ void __launch_bounds__(256) k_gemm1(
    const float* __restrict__ x, const float* __restrict__ W1,
    const float* __restrict__ dinv, float* __restrict__ vs1) {
    __shared__ float w[F_IN * H_MID];   // 8 KB
    __shared__ float xs[16 * 132];      // padded rows
    int t = threadIdx.x;
    for (int i = t; i < F_IN * H_MID; i += 256) w[i] = W1[i];
    int tile = blockIdx.x;              // 6250 tiles, exact
    const float4* xg = (const float4*)(x + (size_t)tile * 16 * F_IN);
    float4* xs4 = (float4*)xs;          // row stride 33 float4
    for (int i = t; i < 512; i += 256) {
        int r = i >> 5, c4 = i & 31;
        xs4[r * 33 + c4] = xg[r * 32 + c4];
    }
    __syncthreads();
    int node = t >> 4, j = t & 15;
    const float* xr = xs + node * 132;
    float acc = 0.f;
#pragma unroll 8
    for (int k = 0; k < F_IN; ++k) acc += xr[k] * w[k * H_MID + j];
    int g = tile * 16 + node;
    vs1[(size_t)g * H_MID + j] = acc * dinv[g];
}

// One bin (64 nodes) per block. MODE 1: out = dinv*relu(dinv*raw + b1)
// (layer-1, produces vs2). MODE 2: out = raw (layer-2, k_out scales).
template<int MODE>
__global__ void __launch_bounds__(256) k_agg(
    const int* __restrict__ off, const unsigned* __restrict__ packed,
    const float* __restrict__ vs, const float* __restrict__ dinv,
    const float* __restrict__ b1, float* __restrict__ outb) {
    __shared__ float acc[BIN_N * H_MID];   // 4 KB
    __shared__ unsigned pk[256];
    int t = threadIdx.x;
    int bin = blockIdx.x;
    for (int i = t; i < BIN_N * H_MID; i += 256) acc[i] = 0.f;
    int a    = off[bin * 8];
    int bEnd = off[(bin + 1) * 8];         // bin's 8 shard segs are contiguous
    int n0 = bin * BIN_N;
    int nN = min(BIN_N, N_NODES - n0);     // last bin: 32 nodes
    __syncthreads();
    int j = t & 15, eslot = t >> 4;        // 16 lanes per edge, 16 edge slots
    for (int base = a; base < bEnd; base += 256) {
        int m = min(256, bEnd - base);
        if (t < m) pk[t] = packed[base + t];
        __syncthreads();
        for (int k = eslot; k < m; k += 16) {
            unsigned p = pk[k];            // broadcast within quarter-wave
            int s  = p & 0x1FFFF;
            int dl = p >> 17;
            atomicAdd(&acc[dl * H_MID + j], vs[(size_t)s * H_MID + j]);
        }
        __syncthreads();
    }
    for (int i = t; i < nN * H_MID; i += 256) {
        int n = n0 + (i >> 4);
        int jj = i & 15;
        float raw = acc[i] + vs[(size_t)n * H_MID + jj];   // + self loop
        if (MODE == 1) {
            float dn = dinv[n];
            outb[(size_t)n * H_MID + jj] = dn * fmaxf(dn * raw + b1[jj], 0.f);
        } else {
            outb[(size_t)n * H_MID + jj] = raw;
        }
    }
}

// out = (dinv*raw2)@W2 + b2 : 16 nodes/block x 40 classes = 640 threads.
__global__ void __launch_bounds__(640) k_out(
    const float* __restrict__ raw2, const float* __restrict__ W2,
    const float* __restrict__ b2, const float* __restrict__ dinv,
    float* __restrict__ out) {
    __shared__ float w2[H_MID * C_OUT];  // 640
    __shared__ float r[16 * 17];         // padded
    int t = threadIdx.x;
    if (t < H_MID * C_OUT) w2[t] = W2[t];
    int tile = blockIdx.x;
    if (t < 256) {
        int node = t >> 4;
        r[node * 17 + (t & 15)] = dinv[tile * 16 + node] * raw2[(size_t)tile * 256 + t];
    }
    __syncthreads();
    int node = t / C_OUT, c = t % C_OUT;
    float acc = 0.f;
#pragma unroll
    for (int jj = 0; jj < H_MID; ++jj) acc += r[node * 17 + jj] * w2[jj * C_OUT + c];
    out[(size_t)(tile * 16 + node) * C_OUT + c] = b2[c] + acc;
}

extern "C" void kernel_launch(void* const* d_in, const int* in_sizes, int n_in,
                              void* d_out, int out_size, void* d_ws, size_t ws_size,
                              hipStream_t stream) {
    const float* x  = (const float*)d_in[0];
    const int*   ei = (const int*)d_in[1];     // [2, E]: row 0 = src, row 1 = dst
    const float* W1 = (const float*)d_in[2];
    const float* b1 = (const float*)d_in[3];
    const float* W2 = (const float*)d_in[4];
    const float* b2 = (const float*)d_in[5];
    float* out = (float*)d_out;

    const int* src = ei;
    const int* dst = ei + N_EDGES;

    // ws (4B units): cnt[100352] | dinv[100352] | histG[12504] | cursor[12504]
    //  | off[12512] | packed[3.2M] | vs1[1.6M] | vs2[1.6M] | raw2[1.6M] ~ 31.4MB
    int*      cnt    = (int*)d_ws;
    float*    dinv   = (float*)(cnt + 100352);
    int*      histG  = (int*)(dinv + 100352);
    int*      cursor = histG + NSEG;
    int*      off    = cursor + NSEG;
    unsigned* packed = (unsigned*)(off + NSEG + 8);
    float*    vs1    = (float*)(packed + N_EDGES);
    float*    vs2    = vs1 + (size_t)N_NODES * H_MID;
    float*    raw2   = vs2 + (size_t)N_NODES * H_MID;

    const int B = 256;
    k_zero   <<<(N_NODES + B - 1) / B, B, 0, stream>>>(cnt, histG);
    k_count  <<<(N_EDGES + B - 1) / B, B, 0, stream>>>(dst, cnt);
    k_dinv   <<<(N_NODES + B - 1) / B, B, 0, stream>>>(cnt, dinv);
    k_hist   <<<FILL_B, B, 0, stream>>>(dst, histG);
    k_scan   <<<1, 1024, 0, stream>>>(histG, off, cursor);
    k_binfill<<<FILL_B, B, 0, stream>>>(src, dst, cursor, packed);
    k_gemm1  <<<N_NODES / 16, B, 0, stream>>>(x, W1, dinv, vs1);
    k_agg<1> <<<NBINS, B, 0, stream>>>(off, packed, vs1, dinv, b1, vs2);
    k_agg<2> <<<NBINS, B, 0, stream>>>(off, packed, vs2, dinv, b1, raw2);
    k_out    <<<N_NODES / 16, 640, 0, stream>>>(raw2, W2, b2, dinv, out);
}

// Round 6
// 1081.645 us; speedup vs baseline: 1.0159x; 1.0159x over previous
//
#include <hip/hip_runtime.h>

// GCN 2-layer: N=100000, F=128 -> H=16 (relu) -> C=40, E=3200000.
// R5 -> R6: k_agg was latency-bound (166 G-loads/s, VALUBusy 3.7%) because
// the dynamic-bound inner loop defeated unrolling -> 1 outstanding gather
// per thread. Rewrite: 16 quarter-wave edge slots x U=8 statically unrolled
// edges per iteration (8 independent gathers in flight per thread), no LDS
// staging of packed[], no barriers in the edge loop. Bin/binfill structure
// kept from R5 (agg WRITE_SIZE 6.25MB confirmed the writeback fix).
//
// Pipeline: cnt/dinv -> hist(bin,shard) -> scan -> binfill(XCD-sharded)
//           -> gemm1 (vs1 = dinv*(x@W1)) -> agg1 (fused relu -> vs2)
//           -> agg2 (raw) -> out = (dinv*raw2)@W2 + b2

#define N_NODES 100000
#define F_IN    128
#define H_MID   16
#define C_OUT   40
#define N_EDGES 3200000

#define BIN_SH   6
#define BIN_N    64                      // nodes per bin
#define NBINS    1563                    // ceil(100000/64)
#define NSEG     (NBINS * 8)             // per-(bin,shard) segments
#define FILL_B   1024                    // fill/hist blocks
#define T_FILL   3125                    // edges per fill block (1024*3125 = E)
#define UAGG     8                       // unrolled edges per slot

__global__ void k_zero(int* __restrict__ cnt, int* __restrict__ histG) {
    int i = blockIdx.x * 256 + threadIdx.x;
    if (i < N_NODES) cnt[i] = 0;
    if (i < NSEG)    histG[i] = 0;
}

__global__ void k_count(const int* __restrict__ dst, int* __restrict__ cnt) {
    int e = blockIdx.x * 256 + threadIdx.x;
    if (e < N_EDGES) atomicAdd(&cnt[dst[e]], 1);
}

__global__ void k_dinv(const int* __restrict__ cnt, float* __restrict__ dinv) {
    int i = blockIdx.x * 256 + threadIdx.x;
    if (i < N_NODES) dinv[i] = rsqrtf(1.0f + (float)cnt[i]);   // +1 = self loop
}

// Per-block LDS histogram over bins, flushed to histG[bin*8 + shard].
__global__ void __launch_bounds__(256) k_hist(const int* __restrict__ dst,
                                              int* __restrict__ histG) {
    __shared__ int h[NBINS];
    int t = threadIdx.x;
    for (int i = t; i < NBINS; i += 256) h[i] = 0;
    __syncthreads();
    size_t e0 = (size_t)blockIdx.x * T_FILL;
    for (int i = t; i < T_FILL; i += 256)
        atomicAdd(&h[dst[e0 + i] >> BIN_SH], 1);
    __syncthreads();
    int shard = blockIdx.x & 7;
    for (int i = t; i < NBINS; i += 256)
        if (h[i]) atomicAdd(&histG[i * 8 + shard], h[i]);
}

// Exclusive scan of histG[NSEG] -> off (+ total at off[NSEG]), cursor copy.
__global__ void __launch_bounds__(1024) k_scan(const int* __restrict__ histG,
                                               int* __restrict__ off,
                                               int* __restrict__ cursor) {
    __shared__ int s[1024];
    const int CH = (NSEG + 1023) / 1024;       // 13
    int t = threadIdx.x;
    int base = t * CH;
    int loc[13];
    int sum = 0;
    for (int i = 0; i < CH; ++i) {
        int idx = base + i;
        int v = (idx < NSEG) ? histG[idx] : 0;
        loc[i] = sum; sum += v;
    }
    s[t] = sum;
    __syncthreads();
    for (int o = 1; o < 1024; o <<= 1) {       // Hillis-Steele inclusive
        int v = (t >= o) ? s[t - o] : 0;
        __syncthreads();
        s[t] += v;
        __syncthreads();
    }
    int pre = (t > 0) ? s[t - 1] : 0;
    for (int i = 0; i < CH; ++i) {
        int idx = base + i;
        if (idx < NSEG) { int o = pre + loc[i]; off[idx] = o; cursor[idx] = o; }
    }
    if (t == 1023) off[NSEG] = pre + sum;      // == E
}

// Fill packed bin segments. shard = blockIdx&7 ~ XCD (round-robin heuristic).
__global__ void __launch_bounds__(256) k_binfill(const int* __restrict__ src,
                                                 const int* __restrict__ dst,
                                                 int* __restrict__ cursor,
                                                 unsigned* __restrict__ packed) {
    int shard = blockIdx.x & 7;
    size_t e0 = (size_t)blockIdx.x * T_FILL;
    for (int i = threadIdx.x; i < T_FILL; i += 256) {
        int d = dst[e0 + i];
        int s = src[e0 + i];
        int bin = d >> BIN_SH;
        int pos = atomicAdd(&cursor[bin * 8 + shard], 1);
        packed[pos] = (unsigned)s | ((unsigned)(d & (BIN_N - 1)) << 17);
    }
}

// vs1 = dinv*(x@W1). 16 nodes x 16 feats per 256-thread block.
__global__ void __launch_bounds__(256) k_gemm1(
    const float* __restrict__ x, const float* __restrict__ W1,
    const float* __restrict__ dinv, float* __restrict__ vs1) {
    __shared__ float w[F_IN * H_MID];   // 8 KB
    __shared__ float xs[16 * 132];      // padded rows
    int t = threadIdx.x;
    for (int i = t; i < F_IN * H_MID; i += 256) w[i] = W1[i];
    int tile = blockIdx.x;              // 6250 tiles, exact
    const float4* xg = (const float4*)(x + (size_t)tile * 16 * F_IN);
    float4* xs4 = (float4*)xs;          // row stride 33 float4
    for (int i = t; i < 512; i += 256) {
        int r = i >> 5, c4 = i & 31;
        xs4[r * 33 + c4] = xg[r * 32 + c4];
    }
    __syncthreads();
    int node = t >> 4, j = t & 15;
    const float* xr = xs + node * 132;
    float acc = 0.f;
#pragma unroll 8
    for (int k = 0; k < F_IN; ++k) acc += xr[k] * w[k * H_MID + j];
    int g = tile * 16 + node;
    vs1[(size_t)g * H_MID + j] = acc * dinv[g];
}

// One bin (64 nodes) per block. 16 quarter-wave edge slots, U=8 unrolled
// edges per slot per iteration -> 8 independent gathers in flight/thread.
// MODE 1: out = dinv*relu(dinv*raw + b1) (layer-1). MODE 2: out = raw.
template<int MODE>
__global__ void __launch_bounds__(256) k_agg(
    const int* __restrict__ off, const unsigned* __restrict__ packed,
    const float* __restrict__ vs, const float* __restrict__ dinv,
    const float* __restrict__ b1, float* __restrict__ outb) {
    __shared__ float acc[BIN_N * H_MID];   // 4 KB
    int t = threadIdx.x;
    int bin = blockIdx.x;
    for (int i = t; i < BIN_N * H_MID; i += 256) acc[i] = 0.f;
    int a    = off[bin * 8];
    int bEnd = off[(bin + 1) * 8];         // bin's 8 shard segs contiguous
    __syncthreads();
    int j = t & 15, slot = t >> 4;         // 16 lanes/edge, 16 slots
    int len = bEnd - a;
    int nfull = len / (16 * UAGG);         // full super-chunks of 128 edges
    for (int c = 0; c < nfull; ++c) {
        int base = a + c * (16 * UAGG) + slot * UAGG;
        unsigned p[UAGG];
        float v[UAGG];
#pragma unroll
        for (int u = 0; u < UAGG; ++u) p[u] = packed[base + u];
#pragma unroll
        for (int u = 0; u < UAGG; ++u)
            v[u] = vs[(size_t)(p[u] & 0x1FFFF) * H_MID + j];
#pragma unroll
        for (int u = 0; u < UAGG; ++u)
            atomicAdd(&acc[(p[u] >> 17) * H_MID + j], v[u]);
    }
    for (int e = a + nfull * (16 * UAGG) + slot; e < bEnd; e += 16) {
        unsigned p = packed[e];
        atomicAdd(&acc[(p >> 17) * H_MID + j], vs[(size_t)(p & 0x1FFFF) * H_MID + j]);
    }
    __syncthreads();
    int n0 = bin * BIN_N;
    int nN = min(BIN_N, N_NODES - n0);     // last bin: 32 nodes
    for (int i = t; i < nN * H_MID; i += 256) {
        int n = n0 + (i >> 4);
        int jj = i & 15;
        float raw = acc[i] + vs[(size_t)n * H_MID + jj];   // + self loop
        if (MODE == 1) {
            float dn = dinv[n];
            outb[(size_t)n * H_MID + jj] = dn * fmaxf(dn * raw + b1[jj], 0.f);
        } else {
            outb[(size_t)n * H_MID + jj] = raw;
        }
    }
}

// out = (dinv*raw2)@W2 + b2 : 16 nodes/block x 40 classes = 640 threads.
__global__ void __launch_bounds__(640) k_out(
    const float* __restrict__ raw2, const float* __restrict__ W2,
    const float* __restrict__ b2, const float* __restrict__ dinv,
    float* __restrict__ out) {
    __shared__ float w2[H_MID * C_OUT];  // 640
    __shared__ float r[16 * 17];         // padded
    int t = threadIdx.x;
    if (t < H_MID * C_OUT) w2[t] = W2[t];
    int tile = blockIdx.x;
    if (t < 256) {
        int node = t >> 4;
        r[node * 17 + (t & 15)] = dinv[tile * 16 + node] * raw2[(size_t)tile * 256 + t];
    }
    __syncthreads();
    int node = t / C_OUT, c = t % C_OUT;
    float acc = 0.f;
#pragma unroll
    for (int jj = 0; jj < H_MID; ++jj) acc += r[node * 17 + jj] * w2[jj * C_OUT + c];
    out[(size_t)(tile * 16 + node) * C_OUT + c] = b2[c] + acc;
}

extern "C" void kernel_launch(void* const* d_in, const int* in_sizes, int n_in,
                              void* d_out, int out_size, void* d_ws, size_t ws_size,
                              hipStream_t stream) {
    const float* x  = (const float*)d_in[0];
    const int*   ei = (const int*)d_in[1];     // [2, E]: row 0 = src, row 1 = dst
    const float* W1 = (const float*)d_in[2];
    const float* b1 = (const float*)d_in[3];
    const float* W2 = (const float*)d_in[4];
    const float* b2 = (const float*)d_in[5];
    float* out = (float*)d_out;

    const int* src = ei;
    const int* dst = ei + N_EDGES;

    // ws (4B units): cnt[100352] | dinv[100352] | histG[12504] | cursor[12504]
    //  | off[12512] | packed[3.2M] | vs1[1.6M] | vs2[1.6M] | raw2[1.6M] ~ 31.4MB
    int*      cnt    = (int*)d_ws;
    float*    dinv   = (float*)(cnt + 100352);
    int*      histG  = (int*)(dinv + 100352);
    int*      cursor = histG + NSEG;
    int*      off    = cursor + NSEG;
    unsigned* packed = (unsigned*)(off + NSEG + 8);
    float*    vs1    = (float*)(packed + N_EDGES);
    float*    vs2    = vs1 + (size_t)N_NODES * H_MID;
    float*    raw2   = vs2 + (size_t)N_NODES * H_MID;

    const int B = 256;
    k_zero   <<<(N_NODES + B - 1) / B, B, 0, stream>>>(cnt, histG);
    k_count  <<<(N_EDGES + B - 1) / B, B, 0, stream>>>(dst, cnt);
    k_dinv   <<<(N_NODES + B - 1) / B, B, 0, stream>>>(cnt, dinv);
    k_hist   <<<FILL_B, B, 0, stream>>>(dst, histG);
    k_scan   <<<1, 1024, 0, stream>>>(histG, off, cursor);
    k_binfill<<<FILL_B, B, 0, stream>>>(src, dst, cursor, packed);
    k_gemm1  <<<N_NODES / 16, B, 0, stream>>>(x, W1, dinv, vs1);
    k_agg<1> <<<NBINS, B, 0, stream>>>(off, packed, vs1, dinv, b1, vs2);
    k_agg<2> <<<NBINS, B, 0, stream>>>(off, packed, vs2, dinv, b1, raw2);
    k_out    <<<N_NODES / 16, 640, 0, stream>>>(raw2, W2, b2, dinv, out);
}

// Round 7
// 973.985 us; speedup vs baseline: 1.1282x; 1.1105x over previous
//
#include <hip/hip_runtime.h>
#include <hip/hip_fp16.h>

// GCN 2-layer: N=100000, F=128 -> H=16 (relu) -> C=40, E=3200000.
// R6 -> R7: k_agg was L2-MISS SERVICE-RATE bound (~10.7 G-lines/s, FETCH
// 92MB for a 6.4MB buffer): vs didn't fit per-XCD 4MB L2. Fix: vs rows in
// fp16 -> 3.2MB, L2-resident per XCD; packed[] loads non-temporal so the
// stream doesn't evict vs. Also: binfill's 3.2M same-address cursor atomics
// (256 hits/address -> channel serialization) replaced by batched per-block
// LDS count + one reservation atomic per (bin,shard) (~200k atomics).
// gemm1: transposed-W (padded) + ds_read_b128.
//
// Pipeline: cnt/dinv -> hist -> scan -> binfill(reserve+place)
//   -> gemm1 (vs1h = fp16(dinv*(x@W1)))
//   -> agg<1> (LDS acc; fused relu -> vs2h fp16) -> agg<2> (raw2 fp32)
//   -> out = (dinv*raw2)@W2 + b2

#define N_NODES 100000
#define F_IN    128
#define H_MID   16
#define C_OUT   40
#define N_EDGES 3200000

#define BIN_SH   6
#define BIN_N    64                      // nodes per bin
#define NBINS    1563                    // ceil(100000/64)
#define NSEG     (NBINS * 8)             // per-(bin,shard) segments
#define FILL_B   128                     // fill/hist blocks
#define T_FILL   25000                   // edges per fill block (128*25000 = E)
#define UAGG     8                       // unrolled edges per slot

__global__ void k_zero(int* __restrict__ cnt, int* __restrict__ histG) {
    int i = blockIdx.x * 256 + threadIdx.x;
    if (i < N_NODES) cnt[i] = 0;
    if (i < NSEG)    histG[i] = 0;
}

__global__ void k_count(const int* __restrict__ dst, int* __restrict__ cnt) {
    int e = blockIdx.x * 256 + threadIdx.x;
    if (e < N_EDGES) atomicAdd(&cnt[dst[e]], 1);
}

__global__ void k_dinv(const int* __restrict__ cnt, float* __restrict__ dinv) {
    int i = blockIdx.x * 256 + threadIdx.x;
    if (i < N_NODES) dinv[i] = rsqrtf(1.0f + (float)cnt[i]);   // +1 = self loop
}

// Per-block LDS histogram over bins, flushed to histG[bin*8 + shard].
__global__ void __launch_bounds__(256) k_hist(const int* __restrict__ dst,
                                              int* __restrict__ histG) {
    __shared__ int h[NBINS];
    int t = threadIdx.x;
    for (int i = t; i < NBINS; i += 256) h[i] = 0;
    __syncthreads();
    size_t e0 = (size_t)blockIdx.x * T_FILL;
    for (int i = t; i < T_FILL; i += 256) {
        int d = __builtin_nontemporal_load(&dst[e0 + i]);
        atomicAdd(&h[d >> BIN_SH], 1);
    }
    __syncthreads();
    int shard = blockIdx.x & 7;
    for (int i = t; i < NBINS; i += 256)
        if (h[i]) atomicAdd(&histG[i * 8 + shard], h[i]);
}

// Exclusive scan of histG[NSEG] -> off (+ total at off[NSEG]), cursor copy.
__global__ void __launch_bounds__(1024) k_scan(const int* __restrict__ histG,
                                               int* __restrict__ off,
                                               int* __restrict__ cursor) {
    __shared__ int s[1024];
    const int CH = (NSEG + 1023) / 1024;       // 13
    int t = threadIdx.x;
    int base = t * CH;
    int loc[13];
    int sum = 0;
    for (int i = 0; i < CH; ++i) {
        int idx = base + i;
        int v = (idx < NSEG) ? histG[idx] : 0;
        loc[i] = sum; sum += v;
    }
    s[t] = sum;
    __syncthreads();
    for (int o = 1; o < 1024; o <<= 1) {       // Hillis-Steele inclusive
        int v = (t >= o) ? s[t - o] : 0;
        __syncthreads();
        s[t] += v;
        __syncthreads();
    }
    int pre = (t > 0) ? s[t - 1] : 0;
    for (int i = 0; i < CH; ++i) {
        int idx = base + i;
        if (idx < NSEG) { int o = pre + loc[i]; off[idx] = o; cursor[idx] = o; }
    }
    if (t == 1023) off[NSEG] = pre + sum;      // == E
}

// Batched-reservation fill: LDS count -> one global atomic per (bin,shard)
// to reserve a contiguous range -> place edges via LDS cursors.
__global__ void __launch_bounds__(256) k_binfill(const int* __restrict__ src,
                                                 const int* __restrict__ dst,
                                                 int* __restrict__ cursor,
                                                 unsigned* __restrict__ packed) {
    __shared__ int h[NBINS];                   // counts, then running cursors
    int t = threadIdx.x;
    int shard = blockIdx.x & 7;
    for (int i = t; i < NBINS; i += 256) h[i] = 0;
    __syncthreads();
    size_t e0 = (size_t)blockIdx.x * T_FILL;
    for (int i = t; i < T_FILL; i += 256) {
        int d = __builtin_nontemporal_load(&dst[e0 + i]);
        atomicAdd(&h[d >> BIN_SH], 1);
    }
    __syncthreads();
    for (int i = t; i < NBINS; i += 256) {
        int c = h[i];
        h[i] = c ? atomicAdd(&cursor[i * 8 + shard], c) : 0;   // -> base offset
    }
    __syncthreads();
    for (int i = t; i < T_FILL; i += 256) {
        int d = __builtin_nontemporal_load(&dst[e0 + i]);
        int s = __builtin_nontemporal_load(&src[e0 + i]);
        int pos = atomicAdd(&h[d >> BIN_SH], 1);               // LDS cursor
        packed[pos] = (unsigned)s | ((unsigned)(d & (BIN_N - 1)) << 17);
    }
}

// vs1h = fp16(dinv*(x@W1)). 16 nodes x 16 feats per 256-thread block.
// W transposed in LDS (padded row 132) -> ds_read_b128 for both operands.
__global__ void __launch_bounds__(256) k_gemm1(
    const float* __restrict__ x, const float* __restrict__ W1,
    const float* __restrict__ dinv, __half* __restrict__ vs1h) {
    __shared__ float wT[H_MID * 132];   // wT[j][k], padded (8.4 KB)
    __shared__ float xs[16 * 132];      // padded rows
    int t = threadIdx.x;
    for (int i = t; i < F_IN * H_MID; i += 256) {
        int k = i >> 4, j = i & 15;     // W1 coalesced read
        wT[j * 132 + k] = W1[i];
    }
    int tile = blockIdx.x;              // 6250 tiles, exact
    const float4* xg = (const float4*)(x + (size_t)tile * 16 * F_IN);
    float4* xs4 = (float4*)xs;          // row stride 33 float4
    for (int i = t; i < 512; i += 256) {
        int r = i >> 5, c4 = i & 31;
        xs4[r * 33 + c4] = xg[r * 32 + c4];
    }
    __syncthreads();
    int node = t >> 4, j = t & 15;
    const float4* xr4 = (const float4*)(xs + node * 132);
    const float4* wr4 = (const float4*)(wT + j * 132);
    float acc = 0.f;
#pragma unroll
    for (int k4 = 0; k4 < 32; ++k4) {
        float4 a = xr4[k4], w = wr4[k4];
        acc += a.x * w.x + a.y * w.y + a.z * w.z + a.w * w.w;
    }
    int g = tile * 16 + node;
    vs1h[(size_t)g * H_MID + j] = __float2half(acc * dinv[g]);
}

// One bin (64 nodes) per block; 16 quarter-wave edge slots x UAGG unrolled.
// vs rows fp16 (32B) -> 3.2MB buffer, L2-resident per XCD.
// MODE 1: out = fp16(dinv*relu(dinv*raw + b1)) (layer-1 -> vs2h).
// MODE 2: out = raw fp32 (layer-2 -> raw2).
template<int MODE>
__global__ void __launch_bounds__(256) k_agg(
    const int* __restrict__ off, const unsigned* __restrict__ packed,
    const __half* __restrict__ vs, const float* __restrict__ dinv,
    const float* __restrict__ b1, void* __restrict__ outb) {
    __shared__ float acc[BIN_N * H_MID];   // 4 KB
    int t = threadIdx.x;
    int bin = blockIdx.x;
    for (int i = t; i < BIN_N * H_MID; i += 256) acc[i] = 0.f;
    int a    = off[bin * 8];
    int bEnd = off[(bin + 1) * 8];         // bin's 8 shard segs contiguous
    __syncthreads();
    int j = t & 15, slot = t >> 4;         // 16 lanes/edge, 16 slots
    int len = bEnd - a;
    int nfull = len / (16 * UAGG);         // full super-chunks of 128 edges
    for (int c = 0; c < nfull; ++c) {
        int base = a + c * (16 * UAGG) + slot * UAGG;
        unsigned p[UAGG];
        float v[UAGG];
#pragma unroll
        for (int u = 0; u < UAGG; ++u)
            p[u] = __builtin_nontemporal_load(&packed[base + u]);
#pragma unroll
        for (int u = 0; u < UAGG; ++u)
            v[u] = __half2float(vs[(size_t)(p[u] & 0x1FFFF) * H_MID + j]);
#pragma unroll
        for (int u = 0; u < UAGG; ++u)
            atomicAdd(&acc[(p[u] >> 17) * H_MID + j], v[u]);
    }
    for (int e = a + nfull * (16 * UAGG) + slot; e < bEnd; e += 16) {
        unsigned p = packed[e];
        atomicAdd(&acc[(p >> 17) * H_MID + j],
                  __half2float(vs[(size_t)(p & 0x1FFFF) * H_MID + j]));
    }
    __syncthreads();
    int n0 = bin * BIN_N;
    int nN = min(BIN_N, N_NODES - n0);     // last bin: 32 nodes
    for (int i = t; i < nN * H_MID; i += 256) {
        int n = n0 + (i >> 4);
        int jj = i & 15;
        float raw = acc[i] + __half2float(vs[(size_t)n * H_MID + jj]); // + self
        if (MODE == 1) {
            float dn = dinv[n];
            ((__half*)outb)[(size_t)n * H_MID + jj] =
                __float2half(dn * fmaxf(dn * raw + b1[jj], 0.f));
        } else {
            ((float*)outb)[(size_t)n * H_MID + jj] = raw;
        }
    }
}

// out = (dinv*raw2)@W2 + b2 : 16 nodes/block x 40 classes = 640 threads.
__global__ void __launch_bounds__(640) k_out(
    const float* __restrict__ raw2, const float* __restrict__ W2,
    const float* __restrict__ b2, const float* __restrict__ dinv,
    float* __restrict__ out) {
    __shared__ float w2[H_MID * C_OUT];  // 640
    __shared__ float r[16 * 17];         // padded
    int t = threadIdx.x;
    if (t < H_MID * C_OUT) w2[t] = W2[t];
    int tile = blockIdx.x;
    if (t < 256) {
        int node = t >> 4;
        r[node * 17 + (t & 15)] = dinv[tile * 16 + node] * raw2[(size_t)tile * 256 + t];
    }
    __syncthreads();
    int node = t / C_OUT, c = t % C_OUT;
    float acc = 0.f;
#pragma unroll
    for (int jj = 0; jj < H_MID; ++jj) acc += r[node * 17 + jj] * w2[jj * C_OUT + c];
    out[(size_t)(tile * 16 + node) * C_OUT + c] = b2[c] + acc;
}

extern "C" void kernel_launch(void* const* d_in, const int* in_sizes, int n_in,
                              void* d_out, int out_size, void* d_ws, size_t ws_size,
                              hipStream_t stream) {
    const float* x  = (const float*)d_in[0];
    const int*   ei = (const int*)d_in[1];     // [2, E]: row 0 = src, row 1 = dst
    const float* W1 = (const float*)d_in[2];
    const float* b1 = (const float*)d_in[3];
    const float* W2 = (const float*)d_in[4];
    const float* b2 = (const float*)d_in[5];
    float* out = (float*)d_out;

    const int* src = ei;
    const int* dst = ei + N_EDGES;

    // ws (4B units): cnt[100352] | dinv[100352] | histG[12504] | cursor[12504]
    //  | off[12512] | packed[3.2M] | vs1h[0.8M u32] | vs2h[0.8M u32] | raw2[1.6M]
    int*      cnt    = (int*)d_ws;
    float*    dinv   = (float*)(cnt + 100352);
    int*      histG  = (int*)(dinv + 100352);
    int*      cursor = histG + NSEG;
    int*      off    = cursor + NSEG;
    unsigned* packed = (unsigned*)(off + NSEG + 8);
    __half*   vs1h   = (__half*)(packed + N_EDGES);
    __half*   vs2h   = vs1h + (size_t)N_NODES * H_MID;
    float*    raw2   = (float*)(vs2h + (size_t)N_NODES * H_MID);

    const int B = 256;
    k_zero   <<<(N_NODES + B - 1) / B, B, 0, stream>>>(cnt, histG);
    k_count  <<<(N_EDGES + B - 1) / B, B, 0, stream>>>(dst, cnt);
    k_dinv   <<<(N_NODES + B - 1) / B, B, 0, stream>>>(cnt, dinv);
    k_hist   <<<FILL_B, B, 0, stream>>>(dst, histG);
    k_scan   <<<1, 1024, 0, stream>>>(histG, off, cursor);
    k_binfill<<<FILL_B, B, 0, stream>>>(src, dst, cursor, packed);
    k_gemm1  <<<N_NODES / 16, B, 0, stream>>>(x, W1, dinv, vs1h);
    k_agg<1> <<<NBINS, B, 0, stream>>>(off, packed, vs1h, dinv, b1, (void*)vs2h);
    k_agg<2> <<<NBINS, B, 0, stream>>>(off, packed, vs2h, dinv, b1, (void*)raw2);
    k_out    <<<N_NODES / 16, 640, 0, stream>>>(raw2, W2, b2, dinv, out);
}